// Round 7
// baseline (267.600 us; speedup 1.0000x reference)
//
#include <hip/hip_runtime.h>
#include <hip/hip_bf16.h>
#include <math.h>

// ---------------------------------------------------------------------------
// RotSSM: out[b,Do,t] = C2 @ scan(M @ u)[.,b,t] + D ⊙ u[b,.,t]
// LCH=16, 2048 blocks per heavy kernel (8 blocks/CU), 3 launches:
//   k0: M/C2 bf16 + tables (32 blocks, redundant per-block precompute)
//   k1: stage u -> GEMM1 -> W scratch (bf16) + in-register weighted totals
//   k3: closed-form carry -> seeded scan (W from L2) -> GEMM2 -> out
// Frag formulas (HW-verified): A[m=L&15][k=(L>>4)*8+j], B[k][n=L&15],
// D col=L&15, row=(L>>4)*4+reg.
// ---------------------------------------------------------------------------

typedef __attribute__((ext_vector_type(8))) short short8;   // 8 bf16 (4 VGPRs)
typedef __attribute__((ext_vector_type(4))) float f32x4;

#define TLEN 4096
#define LCH 16
#define NCH 256
#define BSZ 8
#define LDK 264          // shorts per t-row of u tile (256 + 8 pad)
#define LDW 132          // dwords per t-row of z tile (128 + 4 pad)

// workspace float offsets
constexpr int MB_OFF  = 0;                            // M  bf16 row-major [256][256]
constexpr int CB_OFF  = 32768;                        // C2 bf16 row-major
constexpr int APT_OFF = 65536;                        // a^e, e in [0,16): [16][128] float2
constexpr int ALP_OFF = APT_OFF + 16 * 256;           // (a^16)^k, k in [0,256): [256][128] float2
constexpr int TOT_OFF = ALP_OFF + 256 * 256;          // Tot [256][8][128] float2
constexpr int W_OFF   = TOT_OFF + NCH * BSZ * 256;    // W bf16 pairs [4096][8][128] uint

__device__ __forceinline__ float bfbits2f(unsigned int bits16) {
  union { unsigned int u; float f; } v; v.u = bits16 << 16; return v.f;
}
__device__ __forceinline__ unsigned int f2bfbits(float f) {
  union { float f; unsigned int u; } v; v.f = f;
  return (v.u + 0x7fffu + ((v.u >> 16) & 1u)) >> 16;   // RNE, finite inputs
}
__device__ __forceinline__ unsigned int pack2(float x, float y) {
  return f2bfbits(x) | (f2bfbits(y) << 16);
}

// ---------------------------------------------------------------------------
// K0: merged precompute. 32 blocks; each block redundantly builds gamma/norm/P
// in shared, then writes its M (blk<16) or C2 (blk>=16) slice. Block 0 also
// writes the a-power tables.
// ---------------------------------------------------------------------------
__global__ __launch_bounds__(256) void k0_setup(
    const float* __restrict__ thetas_log, const float* __restrict__ P_param,
    const float* __restrict__ B_param, const float* __restrict__ C,
    const float* __restrict__ gamma_log, float* __restrict__ ws) {
  __shared__ float tracep[64][4];
  __shared__ double gamma_d[64];
  __shared__ float Pl[64][16];
  __shared__ float nrm[64];
  const int blk = blockIdx.x, tid = threadIdx.x;
  {
    const float4* bp = (const float4*)(B_param + tid * 256);
    float s = 0.f;
#pragma unroll 8
    for (int i = 0; i < 64; ++i) {
      float4 v = bp[i];
      s += v.x * v.x + v.y * v.y + v.z * v.z + v.w * v.w;
    }
    tracep[tid >> 2][tid & 3] = s;
  }
  __syncthreads();
  if (tid < 64) {
    int h = tid;
    double g = exp(-exp((double)gamma_log[h]));
    gamma_d[h] = g;
    double tr = (double)tracep[h][0] + tracep[h][1] + tracep[h][2] + tracep[h][3];
    nrm[h] = (float)sqrt((1.0 - g * g) / tr);
    double A[4][4], E[4][4], Tm[4][4];
    for (int i = 0; i < 4; ++i)
      for (int j = 0; j < 4; ++j)
        A[i][j] = (double)P_param[h * 16 + i * 4 + j] - (double)P_param[h * 16 + j * 4 + i];
    double fro = 0.0;
    for (int i = 0; i < 4; ++i) for (int j = 0; j < 4; ++j) fro += A[i][j] * A[i][j];
    fro = sqrt(fro);
    int s = 0;
    while (fro > 0.25 && s < 30) { fro *= 0.5; ++s; }
    double scl = 1.0;
    for (int q2 = 0; q2 < s; ++q2) scl *= 0.5;
    for (int i = 0; i < 4; ++i) for (int j = 0; j < 4; ++j) A[i][j] *= scl;
    for (int i = 0; i < 4; ++i)
      for (int j = 0; j < 4; ++j) { E[i][j] = (i == j) ? 1.0 : 0.0; Tm[i][j] = E[i][j]; }
    for (int k = 1; k <= 16; ++k) {
      double Tn[4][4];
      for (int i = 0; i < 4; ++i)
        for (int j = 0; j < 4; ++j) {
          double acc = 0.0;
          for (int m = 0; m < 4; ++m) acc += Tm[i][m] * A[m][j];
          Tn[i][j] = acc / (double)k;
        }
      for (int i = 0; i < 4; ++i)
        for (int j = 0; j < 4; ++j) { Tm[i][j] = Tn[i][j]; E[i][j] += Tn[i][j]; }
    }
    for (int q2 = 0; q2 < s; ++q2) {
      double E2[4][4];
      for (int i = 0; i < 4; ++i)
        for (int j = 0; j < 4; ++j) {
          double acc = 0.0;
          for (int m = 0; m < 4; ++m) acc += E[i][m] * E[m][j];
          E2[i][j] = acc;
        }
      for (int i = 0; i < 4; ++i) for (int j = 0; j < 4; ++j) E[i][j] = E2[i][j];
    }
    for (int i = 0; i < 4; ++i)
      for (int j = 0; j < 4; ++j) Pl[h][i * 4 + j] = (float)E[i][j];
  }
  __syncthreads();
  if (blk < 16) {
    unsigned short* Mbf = (unsigned short*)(ws + MB_OFF);
    for (int rr = 0; rr < 16; ++rr) {
      int r = blk * 16 + rr, h = r >> 2, N = r & 3;
      float acc = 0.f;
      for (int n = 0; n < 4; ++n)
        acc += Pl[h][N * 4 + n] * B_param[(h * 4 + n) * 256 + tid];
      Mbf[r * 256 + tid] = (unsigned short)f2bfbits(nrm[h] * acc);
    }
  } else {
    unsigned short* Cbf = (unsigned short*)(ws + CB_OFF);
    int h = tid >> 2, N = tid & 3;       // tid = state-column index k = 4h+N
    for (int rr = 0; rr < 16; ++rr) {
      int Do = (blk - 16) * 16 + rr;
      float acc = 0.f;
      for (int n = 0; n < 4; ++n)
        acc += C[Do * 256 + (tid & ~3) + n] * Pl[h][N * 4 + n];
      Cbf[Do * 256 + tid] = (unsigned short)f2bfbits(acc);
    }
  }
  if (blk == 0 && tid < 128) {
    int h = tid >> 1, p = tid & 1;
    double th = exp((double)thetas_log[h * 2 + p]);
    double g = gamma_d[h];
    double ar = g * cos(th), ai = g * sin(th);
    float2* APT = (float2*)(ws + APT_OFF);
    double xr = 1.0, xi = 0.0;
    APT[tid] = make_float2(1.f, 0.f);                 // a^0
    for (int e = 1; e < 16; ++e) {
      double nr = xr * ar - xi * ai, ni = xr * ai + xi * ar;
      xr = nr; xi = ni;
      APT[e * 128 + tid] = make_float2((float)xr, (float)xi);
    }
    // a^16 by one more mul then squaring path: xr = a^15 here
    double br = xr * ar - xi * ai, bi = xr * ai + xi * ar;   // a^16
    float2* ALp = (float2*)(ws + ALP_OFF);
    xr = 1.0; xi = 0.0;
    ALp[tid] = make_float2(1.f, 0.f);
    for (int k = 1; k < NCH; ++k) {
      double nr = xr * br - xi * bi, ni = xr * bi + xi * br;
      xr = nr; xi = ni;
      ALp[k * 128 + tid] = make_float2((float)xr, (float)xi);
    }
  }
}

// ---------------------------------------------------------------------------
// K1: stage u -> GEMM1 -> W scratch (bf16 pairs) + in-register totals.
// Grid (NCH, BSZ) = 2048 blocks, LDS 8448 B, ONE barrier.
// ---------------------------------------------------------------------------
__global__ __launch_bounds__(256) void k1_tot(
    const float* __restrict__ u, float* __restrict__ ws) {
  __shared__ __align__(16) unsigned short us[LCH * LDK];   // 8448 B
  const int c = blockIdx.x, b = blockIdx.y;
  const int t0 = c * LCH;
  const int tid = threadIdx.x;
  const int L = tid & 63;
  const int w = __builtin_amdgcn_readfirstlane(tid >> 6);
  const int qh = L >> 4, l15 = L & 15;

  // stage u[d][t0..t0+15] -> us[t][d ^ ((t&3)<<3)]
  {
    const int dbase = tid >> 2, t4 = (tid & 3) * 4;
#pragma unroll
    for (int i = 0; i < 4; ++i) {
      int d = dbase + i * 64;
      float4 v = *(const float4*)(u + (size_t)(b * 256 + d) * TLEN + t0 + t4);
      float vv[4] = {v.x, v.y, v.z, v.w};
#pragma unroll
      for (int dt = 0; dt < 4; ++dt)
        us[(t4 + dt) * LDK + (d ^ (dt << 3))] = (unsigned short)f2bfbits(vv[dt]);
    }
  }
  __syncthreads();

  // GEMM1: W[256][16] = M @ u_tile
  f32x4 acc[4];
#pragma unroll
  for (int rt = 0; rt < 4; ++rt) acc[rt] = (f32x4){0.f, 0.f, 0.f, 0.f};
  {
    const unsigned short* Mbf = (const unsigned short*)(ws + MB_OFF);
#pragma unroll
    for (int ks = 0; ks < 8; ++ks) {
      short8 af[4];
#pragma unroll
      for (int rt = 0; rt < 4; ++rt)
        af[rt] = *(const short8*)(Mbf + (size_t)(w * 64 + rt * 16 + l15) * 256 + ks * 32 + qh * 8);
      int col = (ks * 32 + qh * 8) ^ ((l15 & 3) << 3);
      short8 bfr = *(const short8*)(us + l15 * LDK + col);
#pragma unroll
      for (int rt = 0; rt < 4; ++rt)
        acc[rt] = __builtin_amdgcn_mfma_f32_16x16x32_bf16(af[rt], bfr, acc[rt], 0, 0, 0);
    }
  }

  // W -> global scratch (bf16 pairs, L2-merged), and in-register totals
  unsigned int* Wg = (unsigned int*)(ws + W_OFF);
  const float2* APT = (const float2*)(ws + APT_OFF);
  float2* Tot = (float2*)(ws + TOT_OFF);
#pragma unroll
  for (int rt = 0; rt < 4; ++rt) {
    int pbase = w * 32 + rt * 8 + qh * 2;     // pair index of acc[rt][0..1]
    uint2 wv = make_uint2(pack2(acc[rt][0], acc[rt][1]), pack2(acc[rt][2], acc[rt][3]));
    *(uint2*)&Wg[((size_t)(t0 + l15) * BSZ + b) * 128 + pbase] = wv;
#pragma unroll
    for (int j = 0; j < 2; ++j) {
      float wre = acc[rt][2 * j], wim = acc[rt][2 * j + 1];
      float2 aw = APT[(15 - l15) * 128 + pbase + j];   // a^{15-t}
      float sr = wre * aw.x - wim * aw.y;
      float si = wre * aw.y + wim * aw.x;
#pragma unroll
      for (int m = 1; m < 16; m <<= 1) {
        sr += __shfl_xor(sr, m);
        si += __shfl_xor(si, m);
      }
      if (l15 == 0)
        Tot[(c * BSZ + b) * 128 + pbase + j] = make_float2(sr, si);
    }
  }
}

// ---------------------------------------------------------------------------
// K3: carry (closed form) -> seeded scan (W from L2) -> z LDS -> GEMM2 -> out.
// Grid (NCH, BSZ) = 2048 blocks, LDS 8448 B, ONE barrier.
// ---------------------------------------------------------------------------
__global__ __launch_bounds__(256) void k3_main(
    const float* __restrict__ u, const float* __restrict__ Dv,
    const float* __restrict__ ws, float* __restrict__ out) {
  __shared__ __align__(16) unsigned int wd[LCH * LDW];    // z tile, 8448 B
  const int c = blockIdx.x, b = blockIdx.y;
  const int t0 = c * LCH;
  const int tid = threadIdx.x;
  const int L = tid & 63;
  const int w = __builtin_amdgcn_readfirstlane(tid >> 6);
  const int qh = L >> 4, l15 = L & 15;

  if (tid < 128) {
    const int p = tid;
    // carry = sum_{cp<c} (a^16)^{c-1-cp} * Tot_{cp}
    float cr = 0.f, ci = 0.f;
    const float2* ALp = (const float2*)(ws + ALP_OFF);
    const float2* Tot = (const float2*)(ws + TOT_OFF);
    for (int cp = 0; cp < c; ++cp) {
      float2 al = ALp[(c - 1 - cp) * 128 + p];
      float2 tv = Tot[(cp * BSZ + b) * 128 + p];
      cr = fmaf(al.x, tv.x, fmaf(-al.y, tv.y, cr));
      ci = fmaf(al.x, tv.y, fmaf(al.y, tv.x, ci));
    }
    // seeded scan: z_{-1} = carry
    const unsigned int* Wg = (const unsigned int*)(ws + W_OFF);
    float2 a = ((const float2*)(ws + APT_OFF))[128 + p];   // a^1
    float zr = cr, zi = ci;
#pragma unroll
    for (int t = 0; t < LCH; ++t) {
      unsigned int wv = Wg[((size_t)(t0 + t) * BSZ + b) * 128 + p];
      float wr = bfbits2f(wv & 0xffffu), wi = bfbits2f(wv >> 16);
      float nr = fmaf(a.x, zr, fmaf(-a.y, zi, wr));
      float ni = fmaf(a.x, zi, fmaf(a.y, zr, wi));
      zr = nr; zi = ni;
      wd[t * LDW + p] = pack2(zr, zi);
    }
  }
  __syncthreads();

  // GEMM2: out_tile = C2 @ Z
  f32x4 acc[4];
#pragma unroll
  for (int rt = 0; rt < 4; ++rt) acc[rt] = (f32x4){0.f, 0.f, 0.f, 0.f};
  {
    const unsigned short* Cbf = (const unsigned short*)(ws + CB_OFF);
    const unsigned short* zs  = (const unsigned short*)wd;
#pragma unroll
    for (int ks = 0; ks < 8; ++ks) {
      short8 af[4];
#pragma unroll
      for (int rt = 0; rt < 4; ++rt)
        af[rt] = *(const short8*)(Cbf + (size_t)(w * 64 + rt * 16 + l15) * 256 + ks * 32 + qh * 8);
      short8 bfr = *(const short8*)(zs + l15 * (LDW * 2) + ks * 32 + qh * 8);
#pragma unroll
      for (int rt = 0; rt < 4; ++rt)
        acc[rt] = __builtin_amdgcn_mfma_f32_16x16x32_bf16(af[rt], bfr, acc[rt], 0, 0, 0);
    }
  }

  // epilogue: out = acc + D ⊙ u (u fp32 from global, L3-warm)
#pragma unroll
  for (int rt = 0; rt < 4; ++rt) {
    int Dbase = w * 64 + rt * 16 + qh * 4;
    size_t obase = (size_t)(b * 256 + Dbase) * TLEN + t0 + l15;
#pragma unroll
    for (int q = 0; q < 4; ++q)
      out[obase + (size_t)q * TLEN] =
          acc[rt][q] + Dv[Dbase + q] * u[obase + (size_t)q * TLEN];
  }
}

extern "C" void kernel_launch(void* const* d_in, const int* in_sizes, int n_in,
                              void* d_out, int out_size, void* d_ws, size_t ws_size,
                              hipStream_t stream) {
  const float* u          = (const float*)d_in[0];
  const float* thetas_log = (const float*)d_in[1];
  const float* P_param    = (const float*)d_in[2];
  const float* B_param    = (const float*)d_in[3];
  const float* C          = (const float*)d_in[4];
  const float* Dvec       = (const float*)d_in[5];
  const float* gamma_log  = (const float*)d_in[6];
  float* out = (float*)d_out;
  float* ws  = (float*)d_ws;

  hipLaunchKernelGGL(k0_setup, dim3(32), dim3(256), 0, stream,
                     thetas_log, P_param, B_param, C, gamma_log, ws);
  hipLaunchKernelGGL(k1_tot, dim3(NCH, BSZ), dim3(256), 0, stream, u, ws);
  hipLaunchKernelGGL(k3_main, dim3(NCH, BSZ), dim3(256), 0, stream, u, Dvec, ws, out);
}

// Round 8
// 197.812 us; speedup vs baseline: 1.3528x; 1.3528x over previous
//
#include <hip/hip_runtime.h>
#include <hip/hip_bf16.h>
#include <math.h>

// ---------------------------------------------------------------------------
// RotSSM: out[b,Do,t] = C2 @ scan(M @ u)[.,b,t] + D ⊙ u[b,.,t]
// Coalescing-first pipeline (LCH=32, NCH=128):
//   k0: M/C2 bf16 row-major + a-power tables (32 blocks, round-7-verified)
//   k1: stage u -> GEMM1 -> W (bf16 pairs) + chunk totals via shfl (1 barrier)
//   k3: closed-form carry -> seeded scan (W coalesced) -> GEMM2 -> outT bf16
//       (B,T,256) fully contiguous
//   k4: transpose outT -> out (B,256,T) + D⊙u; u reads / out writes are
//       full-wave 1 KB contiguous
// Frag formulas (HW-verified): A[m=L&15][k=(L>>4)*8+j], B[k][n=L&15],
// D col=L&15, row=(L>>4)*4+reg.
// ---------------------------------------------------------------------------

typedef __attribute__((ext_vector_type(8))) short short8;   // 8 bf16 (4 VGPRs)
typedef __attribute__((ext_vector_type(4))) float f32x4;

#define TLEN 4096
#define LCH 32
#define NCH 128
#define BSZ 8
#define LDK 264          // shorts per t-row of u/z tile (256 + 8 pad)
#define LDW 132          // dwords per t-row (= LDK/2)

// workspace float offsets
constexpr int MB_OFF  = 0;                      // M  bf16 row-major [256][256]
constexpr int CB_OFF  = 32768;                  // C2 bf16 row-major
constexpr int APT_OFF = 65536;                  // a^e, e in [0,32): [32][128] float2
constexpr int ALP_OFF = 73728;                  // (a^32)^k, k in [0,128): [128][128] float2
constexpr int TOT_OFF = 106496;                 // Tot [128][8][128] float2
constexpr int W_OFF   = 368640;                 // W bf16 pairs [4096][8][128] uint
constexpr int OT_OFF  = 4562944;                // outT bf16 [8][4096][128] uint

__device__ __forceinline__ float bfbits2f(unsigned int bits16) {
  union { unsigned int u; float f; } v; v.u = bits16 << 16; return v.f;
}
__device__ __forceinline__ unsigned int f2bfbits(float f) {
  union { float f; unsigned int u; } v; v.f = f;
  return (v.u + 0x7fffu + ((v.u >> 16) & 1u)) >> 16;   // RNE, finite inputs
}
__device__ __forceinline__ unsigned int pack2(float x, float y) {
  return f2bfbits(x) | (f2bfbits(y) << 16);
}

// ---------------------------------------------------------------------------
// K0: merged precompute (round-7 verified structure). 32 blocks.
// ---------------------------------------------------------------------------
__global__ __launch_bounds__(256) void k0_setup(
    const float* __restrict__ thetas_log, const float* __restrict__ P_param,
    const float* __restrict__ B_param, const float* __restrict__ C,
    const float* __restrict__ gamma_log, float* __restrict__ ws) {
  __shared__ float tracep[64][4];
  __shared__ double gamma_d[64];
  __shared__ float Pl[64][16];
  __shared__ float nrm[64];
  const int blk = blockIdx.x, tid = threadIdx.x;
  {
    const float4* bp = (const float4*)(B_param + tid * 256);
    float s = 0.f;
#pragma unroll 8
    for (int i = 0; i < 64; ++i) {
      float4 v = bp[i];
      s += v.x * v.x + v.y * v.y + v.z * v.z + v.w * v.w;
    }
    tracep[tid >> 2][tid & 3] = s;
  }
  __syncthreads();
  if (tid < 64) {
    int h = tid;
    double g = exp(-exp((double)gamma_log[h]));
    gamma_d[h] = g;
    double tr = (double)tracep[h][0] + tracep[h][1] + tracep[h][2] + tracep[h][3];
    nrm[h] = (float)sqrt((1.0 - g * g) / tr);
    double A[4][4], E[4][4], Tm[4][4];
    for (int i = 0; i < 4; ++i)
      for (int j = 0; j < 4; ++j)
        A[i][j] = (double)P_param[h * 16 + i * 4 + j] - (double)P_param[h * 16 + j * 4 + i];
    double fro = 0.0;
    for (int i = 0; i < 4; ++i) for (int j = 0; j < 4; ++j) fro += A[i][j] * A[i][j];
    fro = sqrt(fro);
    int s = 0;
    while (fro > 0.25 && s < 30) { fro *= 0.5; ++s; }
    double scl = 1.0;
    for (int q2 = 0; q2 < s; ++q2) scl *= 0.5;
    for (int i = 0; i < 4; ++i) for (int j = 0; j < 4; ++j) A[i][j] *= scl;
    for (int i = 0; i < 4; ++i)
      for (int j = 0; j < 4; ++j) { E[i][j] = (i == j) ? 1.0 : 0.0; Tm[i][j] = E[i][j]; }
    for (int k = 1; k <= 16; ++k) {
      double Tn[4][4];
      for (int i = 0; i < 4; ++i)
        for (int j = 0; j < 4; ++j) {
          double acc = 0.0;
          for (int m = 0; m < 4; ++m) acc += Tm[i][m] * A[m][j];
          Tn[i][j] = acc / (double)k;
        }
      for (int i = 0; i < 4; ++i)
        for (int j = 0; j < 4; ++j) { Tm[i][j] = Tn[i][j]; E[i][j] += Tn[i][j]; }
    }
    for (int q2 = 0; q2 < s; ++q2) {
      double E2[4][4];
      for (int i = 0; i < 4; ++i)
        for (int j = 0; j < 4; ++j) {
          double acc = 0.0;
          for (int m = 0; m < 4; ++m) acc += E[i][m] * E[m][j];
          E2[i][j] = acc;
        }
      for (int i = 0; i < 4; ++i) for (int j = 0; j < 4; ++j) E[i][j] = E2[i][j];
    }
    for (int i = 0; i < 4; ++i)
      for (int j = 0; j < 4; ++j) Pl[h][i * 4 + j] = (float)E[i][j];
  }
  __syncthreads();
  if (blk < 16) {
    unsigned short* Mbf = (unsigned short*)(ws + MB_OFF);
    for (int rr = 0; rr < 16; ++rr) {
      int r = blk * 16 + rr, h = r >> 2, N = r & 3;
      float acc = 0.f;
      for (int n = 0; n < 4; ++n)
        acc += Pl[h][N * 4 + n] * B_param[(h * 4 + n) * 256 + tid];
      Mbf[r * 256 + tid] = (unsigned short)f2bfbits(nrm[h] * acc);
    }
  } else {
    unsigned short* Cbf = (unsigned short*)(ws + CB_OFF);
    int h = tid >> 2, N = tid & 3;       // tid = state-column index k = 4h+N
    for (int rr = 0; rr < 16; ++rr) {
      int Do = (blk - 16) * 16 + rr;
      float acc = 0.f;
      for (int n = 0; n < 4; ++n)
        acc += C[Do * 256 + (tid & ~3) + n] * Pl[h][N * 4 + n];
      Cbf[Do * 256 + tid] = (unsigned short)f2bfbits(acc);
    }
  }
  if (blk == 0 && tid < 128) {
    int h = tid >> 1, p = tid & 1;
    double th = exp((double)thetas_log[h * 2 + p]);
    double g = gamma_d[h];
    double ar = g * cos(th), ai = g * sin(th);
    float2* APT = (float2*)(ws + APT_OFF);
    double xr = 1.0, xi = 0.0;
    APT[tid] = make_float2(1.f, 0.f);                 // a^0
    for (int e = 1; e < LCH; ++e) {
      double nr = xr * ar - xi * ai, ni = xr * ai + xi * ar;
      xr = nr; xi = ni;
      APT[e * 128 + tid] = make_float2((float)xr, (float)xi);
    }
    double br = xr * ar - xi * ai, bi = xr * ai + xi * ar;   // a^32
    float2* ALp = (float2*)(ws + ALP_OFF);
    xr = 1.0; xi = 0.0;
    ALp[tid] = make_float2(1.f, 0.f);
    for (int k = 1; k < NCH; ++k) {
      double nr = xr * br - xi * bi, ni = xr * bi + xi * br;
      xr = nr; xi = ni;
      ALp[k * 128 + tid] = make_float2((float)xr, (float)xi);
    }
  }
}

// ---------------------------------------------------------------------------
// K1: stage u -> GEMM1 -> W (bf16 pairs) + in-register totals. One barrier.
// Grid (NCH, BSZ) = 1024 blocks, LDS 16896 B.
// ---------------------------------------------------------------------------
__global__ __launch_bounds__(256) void k1_tot(
    const float* __restrict__ u, float* __restrict__ ws) {
  __shared__ __align__(16) unsigned short us[LCH * LDK];   // 16896 B
  const int c = blockIdx.x, b = blockIdx.y;
  const int t0 = c * LCH;
  const int tid = threadIdx.x;
  const int L = tid & 63;
  const int w = __builtin_amdgcn_readfirstlane(tid >> 6);
  const int qh = L >> 4, l15 = L & 15;

  // stage u[d][t0..t0+31] -> us[t][d ^ ((t&3)<<3)]  (round-5 verified)
  {
    const int kbase = tid >> 3, t4 = (tid & 7) * 4;
#pragma unroll
    for (int i = 0; i < 8; ++i) {
      int d = kbase + i * 32;
      float4 v = *(const float4*)(u + (size_t)(b * 256 + d) * TLEN + t0 + t4);
      float vv[4] = {v.x, v.y, v.z, v.w};
#pragma unroll
      for (int dt = 0; dt < 4; ++dt)
        us[(t4 + dt) * LDK + (d ^ (dt << 3))] = (unsigned short)f2bfbits(vv[dt]);
    }
  }
  __syncthreads();

  // GEMM1: W[256][32] = M @ u_tile  (round-5 verified)
  f32x4 acc[4][2];
#pragma unroll
  for (int rt = 0; rt < 4; ++rt)
#pragma unroll
    for (int tt = 0; tt < 2; ++tt) acc[rt][tt] = (f32x4){0.f, 0.f, 0.f, 0.f};
  {
    const unsigned short* Mbf = (const unsigned short*)(ws + MB_OFF);
#pragma unroll
    for (int ks = 0; ks < 8; ++ks) {
      short8 af[4], bfr[2];
#pragma unroll
      for (int rt = 0; rt < 4; ++rt)
        af[rt] = *(const short8*)(Mbf + (size_t)(w * 64 + rt * 16 + l15) * 256 + ks * 32 + qh * 8);
#pragma unroll
      for (int tt = 0; tt < 2; ++tt) {
        int row = tt * 16 + l15;
        int col = (ks * 32 + qh * 8) ^ ((row & 3) << 3);
        bfr[tt] = *(const short8*)(us + row * LDK + col);
      }
#pragma unroll
      for (int rt = 0; rt < 4; ++rt)
#pragma unroll
        for (int tt = 0; tt < 2; ++tt)
          acc[rt][tt] = __builtin_amdgcn_mfma_f32_16x16x32_bf16(af[rt], bfr[tt], acc[rt][tt], 0, 0, 0);
    }
  }

  // W -> global (bf16 pairs [t][b][p]); totals Tot_c = sum_t a^{31-t} w_t
  unsigned int* Wg = (unsigned int*)(ws + W_OFF);
  const float2* APT = (const float2*)(ws + APT_OFF);
  float2* Tot = (float2*)(ws + TOT_OFF);
#pragma unroll
  for (int rt = 0; rt < 4; ++rt) {
    int pbase = w * 32 + rt * 8 + qh * 2;
    float s0r = 0.f, s0i = 0.f, s1r = 0.f, s1i = 0.f;
#pragma unroll
    for (int tt = 0; tt < 2; ++tt) {
      int t = tt * 16 + l15;
      f32x4 a4 = acc[rt][tt];
      uint2 wv = make_uint2(pack2(a4[0], a4[1]), pack2(a4[2], a4[3]));
      *(uint2*)&Wg[((size_t)(t0 + t) * BSZ + b) * 128 + pbase] = wv;
      float2 awa = APT[(LCH - 1 - t) * 128 + pbase];
      float2 awb = APT[(LCH - 1 - t) * 128 + pbase + 1];
      s0r += a4[0] * awa.x - a4[1] * awa.y;
      s0i += a4[0] * awa.y + a4[1] * awa.x;
      s1r += a4[2] * awb.x - a4[3] * awb.y;
      s1i += a4[2] * awb.y + a4[3] * awb.x;
    }
#pragma unroll
    for (int m = 1; m < 16; m <<= 1) {
      s0r += __shfl_xor(s0r, m); s0i += __shfl_xor(s0i, m);
      s1r += __shfl_xor(s1r, m); s1i += __shfl_xor(s1i, m);
    }
    if (l15 == 0) {
      Tot[(c * BSZ + b) * 128 + pbase]     = make_float2(s0r, s0i);
      Tot[(c * BSZ + b) * 128 + pbase + 1] = make_float2(s1r, s1i);
    }
  }
}

// ---------------------------------------------------------------------------
// K3: carry -> seeded scan (W coalesced) -> z LDS -> GEMM2 -> outT bf16.
// Grid (NCH, BSZ) = 1024 blocks, LDS 16896 B.
// ---------------------------------------------------------------------------
__global__ __launch_bounds__(256) void k3_main(
    const float* __restrict__ ws_c, float* __restrict__ ws) {
  __shared__ __align__(16) unsigned int wd[LCH * LDW];    // 16896 B
  const int c = blockIdx.x, b = blockIdx.y;
  const int t0 = c * LCH;
  const int tid = threadIdx.x;
  const int L = tid & 63;
  const int w = __builtin_amdgcn_readfirstlane(tid >> 6);
  const int qh = L >> 4, l15 = L & 15;

  if (tid < 128) {
    const int p = tid;
    // carry = sum_{cp<c} (a^32)^{c-1-cp} * Tot_{cp}
    float cr = 0.f, ci = 0.f;
    const float2* ALp = (const float2*)(ws_c + ALP_OFF);
    const float2* Tot = (const float2*)(ws_c + TOT_OFF);
    for (int cp = 0; cp < c; ++cp) {
      float2 al = ALp[(c - 1 - cp) * 128 + p];
      float2 tv = Tot[(cp * BSZ + b) * 128 + p];
      cr = fmaf(al.x, tv.x, fmaf(-al.y, tv.y, cr));
      ci = fmaf(al.x, tv.y, fmaf(al.y, tv.x, ci));
    }
    // seeded scan: z_{-1} = carry
    const unsigned int* Wg = (const unsigned int*)(ws_c + W_OFF);
    float2 a = ((const float2*)(ws_c + APT_OFF))[128 + p];   // a^1
    float zr = cr, zi = ci;
#pragma unroll
    for (int t = 0; t < LCH; ++t) {
      unsigned int wv = Wg[((size_t)(t0 + t) * BSZ + b) * 128 + p];
      float wr = bfbits2f(wv & 0xffffu), wi = bfbits2f(wv >> 16);
      float nr = fmaf(a.x, zr, fmaf(-a.y, zi, wr));
      float ni = fmaf(a.x, zi, fmaf(a.y, zr, wi));
      zr = nr; zi = ni;
      wd[t * LDW + p] = pack2(zr, zi);
    }
  }
  __syncthreads();

  // GEMM2: out_tile = C2 @ Z  (round-4 verified)
  f32x4 acc[4][2];
#pragma unroll
  for (int rt = 0; rt < 4; ++rt)
#pragma unroll
    for (int tt = 0; tt < 2; ++tt) acc[rt][tt] = (f32x4){0.f, 0.f, 0.f, 0.f};
  {
    const unsigned short* Cbf = (const unsigned short*)(ws_c + CB_OFF);
    const unsigned short* zs  = (const unsigned short*)wd;
#pragma unroll
    for (int ks = 0; ks < 8; ++ks) {
      short8 af[4], bfr[2];
#pragma unroll
      for (int rt = 0; rt < 4; ++rt)
        af[rt] = *(const short8*)(Cbf + (size_t)(w * 64 + rt * 16 + l15) * 256 + ks * 32 + qh * 8);
#pragma unroll
      for (int tt = 0; tt < 2; ++tt)
        bfr[tt] = *(const short8*)(zs + (tt * 16 + l15) * LDK + ks * 32 + qh * 8);
#pragma unroll
      for (int rt = 0; rt < 4; ++rt)
#pragma unroll
        for (int tt = 0; tt < 2; ++tt)
          acc[rt][tt] = __builtin_amdgcn_mfma_f32_16x16x32_bf16(af[rt], bfr[tt], acc[rt][tt], 0, 0, 0);
    }
  }
  __syncthreads();   // all z reads done before overwrite

  // acc (D-layout) -> LDS as bf16 [t][Do], then contiguous copy to outT
#pragma unroll
  for (int rt = 0; rt < 4; ++rt) {
    int uidx = w * 32 + rt * 8 + qh * 2;
#pragma unroll
    for (int tt = 0; tt < 2; ++tt) {
      int t = tt * 16 + l15;
      f32x4 a4 = acc[rt][tt];
      wd[t * LDW + uidx]     = pack2(a4[0], a4[1]);
      wd[t * LDW + uidx + 1] = pack2(a4[2], a4[3]);
    }
  }
  __syncthreads();
  {
    unsigned int* OTg = (unsigned int*)(ws + OT_OFF);
#pragma unroll
    for (int i = 0; i < 16; ++i) {
      int idx = tid + i * 256;            // 32 rows x 128 uints
      int t = idx >> 7, col = idx & 127;
      OTg[((size_t)(b * TLEN + t0 + t)) * 128 + col] = wd[t * LDW + col];
    }
  }
}

// ---------------------------------------------------------------------------
// K4: out[b][Do][t] = bf2f(outT[b][t][Do]) + D[Do]*u[b][Do][t].
// Tile 256t x 64Do via LDS; u reads / out writes are 1 KB contiguous.
// Grid (16 tc, 4 dc, 8 b) = 512 blocks, LDS 33792 B.
// ---------------------------------------------------------------------------
__global__ __launch_bounds__(256) void k4_out(
    const float* __restrict__ u, const float* __restrict__ Dv,
    const float* __restrict__ ws, float* __restrict__ out) {
  __shared__ unsigned short tile[256 * 66];   // [t][Do_local], pad 2
  const int tc = blockIdx.x, dc = blockIdx.y, b = blockIdx.z;
  const int tid = threadIdx.x;
  const unsigned int* OTg = (const unsigned int*)(ws + OT_OFF);

  // read outT: per t-row, 32 uints (64 Do) -> LDS
#pragma unroll
  for (int i = 0; i < 32; ++i) {
    int idx = tid + i * 256;               // 256 t x 32 uints
    int t = idx >> 5, col = idx & 31;
    unsigned int v = OTg[((size_t)(b * TLEN + tc * 256 + t)) * 128 + dc * 32 + col];
    *(unsigned int*)(tile + t * 66 + 2 * col) = v;
  }
  __syncthreads();

  // write out: wave handles one Do row (256 t = 1 KB contiguous)
  const int w = tid >> 6, lane = tid & 63;
#pragma unroll
  for (int i = 0; i < 16; ++i) {
    int dl = i * 4 + w;
    int Do = dc * 64 + dl;
    float dv = Dv[Do];
    size_t base = (size_t)(b * 256 + Do) * TLEN + tc * 256 + lane * 4;
    float4 uu = *(const float4*)(u + base);
    float4 o;
    o.x = bfbits2f(tile[(lane * 4 + 0) * 66 + dl]) + dv * uu.x;
    o.y = bfbits2f(tile[(lane * 4 + 1) * 66 + dl]) + dv * uu.y;
    o.z = bfbits2f(tile[(lane * 4 + 2) * 66 + dl]) + dv * uu.z;
    o.w = bfbits2f(tile[(lane * 4 + 3) * 66 + dl]) + dv * uu.w;
    *(float4*)(out + base) = o;
  }
}

extern "C" void kernel_launch(void* const* d_in, const int* in_sizes, int n_in,
                              void* d_out, int out_size, void* d_ws, size_t ws_size,
                              hipStream_t stream) {
  const float* u          = (const float*)d_in[0];
  const float* thetas_log = (const float*)d_in[1];
  const float* P_param    = (const float*)d_in[2];
  const float* B_param    = (const float*)d_in[3];
  const float* C          = (const float*)d_in[4];
  const float* Dvec       = (const float*)d_in[5];
  const float* gamma_log  = (const float*)d_in[6];
  float* out = (float*)d_out;
  float* ws  = (float*)d_ws;

  hipLaunchKernelGGL(k0_setup, dim3(32), dim3(256), 0, stream,
                     thetas_log, P_param, B_param, C, gamma_log, ws);
  hipLaunchKernelGGL(k1_tot, dim3(NCH, BSZ), dim3(256), 0, stream, u, ws);
  hipLaunchKernelGGL(k3_main, dim3(NCH, BSZ), dim3(256), 0, stream, ws, ws);
  hipLaunchKernelGGL(k4_out, dim3(16, 4, BSZ), dim3(256), 0, stream,
                     u, Dvec, ws, out);
}

// Round 9
// 191.992 us; speedup vs baseline: 1.3938x; 1.0303x over previous
//
#include <hip/hip_runtime.h>
#include <hip/hip_bf16.h>
#include <math.h>

// ---------------------------------------------------------------------------
// RotSSM: out[b,Do,t] = C2 @ scan(M @ u)[.,b,t] + D ⊙ u[b,.,t]
// Round-9 pipeline (LCH=32, NCH=128), 4 launches:
//   k0t: blocks<32 = precompute M/C2/tables (round-7 verified);
//        blocks>=32 = transpose u -> uT bf16 [b][t][d] (coalesced both sides)
//   k1 : GEMM1 (B-frags direct from uT global) -> W [c][b][t][p] coalesced
//        via LDS transpose + chunk totals via shfl (1 barrier)
//   k3 : carry (2-half split + ILP-4 reduction) -> seeded scan (W contiguous)
//        -> GEMM2 -> outT bf16 (verified)
//   k4 : outT transpose + D⊙u epilogue (round-8 verbatim)
// Frag formulas (HW-verified): A[m=L&15][k=(L>>4)*8+j], B[k][n=L&15],
// D col=L&15, row=(L>>4)*4+reg.
// ---------------------------------------------------------------------------

typedef __attribute__((ext_vector_type(8))) short short8;   // 8 bf16 (4 VGPRs)
typedef __attribute__((ext_vector_type(4))) float f32x4;

#define TLEN 4096
#define LCH 32
#define NCH 128
#define BSZ 8
#define LDK 264          // shorts per t-row of z tile (256 + 8 pad)
#define LDW 132          // dwords per t-row (= LDK/2)

// workspace float offsets
constexpr int MB_OFF  = 0;                      // M  bf16 row-major [256][256]
constexpr int CB_OFF  = 32768;                  // C2 bf16 row-major
constexpr int APT_OFF = 65536;                  // a^e, e in [0,32): [32][128] float2
constexpr int ALP_OFF = 73728;                  // (a^32)^k, k in [0,128): [128][128] float2
constexpr int TOT_OFF = 106496;                 // Tot [128][8][128] float2
constexpr int W_OFF   = 368640;                 // W bf16 pairs [c][b][t][p] uint
constexpr int OT_OFF  = 4562944;                // outT bf16 [8][4096][128] uint
constexpr int UT_OFF  = 8757248;                // uT  bf16 [8][4096][128] uint

__device__ __forceinline__ float bfbits2f(unsigned int bits16) {
  union { unsigned int u; float f; } v; v.u = bits16 << 16; return v.f;
}
__device__ __forceinline__ unsigned int f2bfbits(float f) {
  union { float f; unsigned int u; } v; v.f = f;
  return (v.u + 0x7fffu + ((v.u >> 16) & 1u)) >> 16;   // RNE, finite inputs
}
__device__ __forceinline__ unsigned int pack2(float x, float y) {
  return f2bfbits(x) | (f2bfbits(y) << 16);
}

// ---------------------------------------------------------------------------
// K0T: blk<32 -> merged precompute (round-7 verified). blk>=32 -> u transpose.
// Grid 544 blocks.
// ---------------------------------------------------------------------------
__global__ __launch_bounds__(256) void k0t_setup(
    const float* __restrict__ thetas_log, const float* __restrict__ P_param,
    const float* __restrict__ B_param, const float* __restrict__ C,
    const float* __restrict__ gamma_log, const float* __restrict__ u,
    float* __restrict__ ws) {
  __shared__ unsigned short tile[256][66];
  const int blk = blockIdx.x, tid = threadIdx.x;
  if (blk >= 32) {
    // ---- u[b][d][t0..t0+63] -> uT[b][t][d] bf16 ----
    const int idxb = blk - 32;           // 0..511
    const int tc = idxb >> 3, b = idxb & 7;
    const int t0 = tc * 64;
    const int dg = tid >> 4, tq = tid & 15;
#pragma unroll
    for (int i = 0; i < 16; ++i) {
      int d = dg + i * 16;
      float4 v = *(const float4*)(u + (size_t)(b * 256 + d) * TLEN + t0 + tq * 4);
      tile[d][tq * 4 + 0] = (unsigned short)f2bfbits(v.x);
      tile[d][tq * 4 + 1] = (unsigned short)f2bfbits(v.y);
      tile[d][tq * 4 + 2] = (unsigned short)f2bfbits(v.z);
      tile[d][tq * 4 + 3] = (unsigned short)f2bfbits(v.w);
    }
    __syncthreads();
    unsigned int* UT = (unsigned int*)(ws + UT_OFF);
#pragma unroll
    for (int i = 0; i < 32; ++i) {
      int idx = tid + i * 256;           // 64 t-rows x 128 dwords
      int t = idx >> 7, dw = idx & 127;
      unsigned int v = (unsigned int)tile[2 * dw][t] |
                       ((unsigned int)tile[2 * dw + 1][t] << 16);
      UT[((size_t)(b * TLEN + t0 + t)) * 128 + dw] = v;
    }
    return;
  }
  // ---- precompute (round-7 verified) ----
  __shared__ float tracep[64][4];
  __shared__ double gamma_d[64];
  __shared__ float Pl[64][16];
  __shared__ float nrm[64];
  {
    const float4* bp = (const float4*)(B_param + tid * 256);
    float s = 0.f;
#pragma unroll 8
    for (int i = 0; i < 64; ++i) {
      float4 v = bp[i];
      s += v.x * v.x + v.y * v.y + v.z * v.z + v.w * v.w;
    }
    tracep[tid >> 2][tid & 3] = s;
  }
  __syncthreads();
  if (tid < 64) {
    int h = tid;
    double g = exp(-exp((double)gamma_log[h]));
    gamma_d[h] = g;
    double tr = (double)tracep[h][0] + tracep[h][1] + tracep[h][2] + tracep[h][3];
    nrm[h] = (float)sqrt((1.0 - g * g) / tr);
    double A[4][4], E[4][4], Tm[4][4];
    for (int i = 0; i < 4; ++i)
      for (int j = 0; j < 4; ++j)
        A[i][j] = (double)P_param[h * 16 + i * 4 + j] - (double)P_param[h * 16 + j * 4 + i];
    double fro = 0.0;
    for (int i = 0; i < 4; ++i) for (int j = 0; j < 4; ++j) fro += A[i][j] * A[i][j];
    fro = sqrt(fro);
    int s = 0;
    while (fro > 0.25 && s < 30) { fro *= 0.5; ++s; }
    double scl = 1.0;
    for (int q2 = 0; q2 < s; ++q2) scl *= 0.5;
    for (int i = 0; i < 4; ++i) for (int j = 0; j < 4; ++j) A[i][j] *= scl;
    for (int i = 0; i < 4; ++i)
      for (int j = 0; j < 4; ++j) { E[i][j] = (i == j) ? 1.0 : 0.0; Tm[i][j] = E[i][j]; }
    for (int k = 1; k <= 16; ++k) {
      double Tn[4][4];
      for (int i = 0; i < 4; ++i)
        for (int j = 0; j < 4; ++j) {
          double acc = 0.0;
          for (int m = 0; m < 4; ++m) acc += Tm[i][m] * A[m][j];
          Tn[i][j] = acc / (double)k;
        }
      for (int i = 0; i < 4; ++i)
        for (int j = 0; j < 4; ++j) { Tm[i][j] = Tn[i][j]; E[i][j] += Tn[i][j]; }
    }
    for (int q2 = 0; q2 < s; ++q2) {
      double E2[4][4];
      for (int i = 0; i < 4; ++i)
        for (int j = 0; j < 4; ++j) {
          double acc = 0.0;
          for (int m = 0; m < 4; ++m) acc += E[i][m] * E[m][j];
          E2[i][j] = acc;
        }
      for (int i = 0; i < 4; ++i) for (int j = 0; j < 4; ++j) E[i][j] = E2[i][j];
    }
    for (int i = 0; i < 4; ++i)
      for (int j = 0; j < 4; ++j) Pl[h][i * 4 + j] = (float)E[i][j];
  }
  __syncthreads();
  if (blk < 16) {
    unsigned short* Mbf = (unsigned short*)(ws + MB_OFF);
    for (int rr = 0; rr < 16; ++rr) {
      int r = blk * 16 + rr, h = r >> 2, N = r & 3;
      float acc = 0.f;
      for (int n = 0; n < 4; ++n)
        acc += Pl[h][N * 4 + n] * B_param[(h * 4 + n) * 256 + tid];
      Mbf[r * 256 + tid] = (unsigned short)f2bfbits(nrm[h] * acc);
    }
  } else {
    unsigned short* Cbf = (unsigned short*)(ws + CB_OFF);
    int h = tid >> 2, N = tid & 3;       // tid = state-column index k = 4h+N
    for (int rr = 0; rr < 16; ++rr) {
      int Do = (blk - 16) * 16 + rr;
      float acc = 0.f;
      for (int n = 0; n < 4; ++n)
        acc += C[Do * 256 + (tid & ~3) + n] * Pl[h][N * 4 + n];
      Cbf[Do * 256 + tid] = (unsigned short)f2bfbits(acc);
    }
  }
  if (blk == 0 && tid < 128) {
    int h = tid >> 1, p = tid & 1;
    double th = exp((double)thetas_log[h * 2 + p]);
    double g = gamma_d[h];
    double ar = g * cos(th), ai = g * sin(th);
    float2* APT = (float2*)(ws + APT_OFF);
    double xr = 1.0, xi = 0.0;
    APT[tid] = make_float2(1.f, 0.f);                 // a^0
    for (int e = 1; e < LCH; ++e) {
      double nr = xr * ar - xi * ai, ni = xr * ai + xi * ar;
      xr = nr; xi = ni;
      APT[e * 128 + tid] = make_float2((float)xr, (float)xi);
    }
    double br = xr * ar - xi * ai, bi = xr * ai + xi * ar;   // a^32
    float2* ALp = (float2*)(ws + ALP_OFF);
    xr = 1.0; xi = 0.0;
    ALp[tid] = make_float2(1.f, 0.f);
    for (int k = 1; k < NCH; ++k) {
      double nr = xr * br - xi * bi, ni = xr * bi + xi * br;
      xr = nr; xi = ni;
      ALp[k * 128 + tid] = make_float2((float)xr, (float)xi);
    }
  }
}

// ---------------------------------------------------------------------------
// K1: GEMM1 (B-frags direct from uT) -> W [c][b][t][p] via LDS + totals.
// Grid (NCH, BSZ) = 1024 blocks, LDS 16.9 KB, ONE barrier.
// ---------------------------------------------------------------------------
__global__ __launch_bounds__(256) void k1_tot(float* __restrict__ ws) {
  __shared__ __align__(16) unsigned int wd[LCH * LDW];
  const int c = blockIdx.x, b = blockIdx.y;
  const int t0 = c * LCH;
  const int tid = threadIdx.x;
  const int L = tid & 63;
  const int w = __builtin_amdgcn_readfirstlane(tid >> 6);
  const int qh = L >> 4, l15 = L & 15;

  // GEMM1: W[256][32] = M @ u_tile (B-frags straight from uT global)
  f32x4 acc[4][2];
#pragma unroll
  for (int rt = 0; rt < 4; ++rt)
#pragma unroll
    for (int tt = 0; tt < 2; ++tt) acc[rt][tt] = (f32x4){0.f, 0.f, 0.f, 0.f};
  {
    const unsigned short* Mbf = (const unsigned short*)(ws + MB_OFF);
    const unsigned short* uT  = (const unsigned short*)(ws + UT_OFF);
#pragma unroll
    for (int ks = 0; ks < 8; ++ks) {
      short8 af[4], bfr[2];
#pragma unroll
      for (int rt = 0; rt < 4; ++rt)
        af[rt] = *(const short8*)(Mbf + (size_t)(w * 64 + rt * 16 + l15) * 256 + ks * 32 + qh * 8);
#pragma unroll
      for (int tt = 0; tt < 2; ++tt)
        bfr[tt] = *(const short8*)(uT + ((size_t)(b * TLEN + t0 + tt * 16 + l15)) * 256 + ks * 32 + qh * 8);
#pragma unroll
      for (int rt = 0; rt < 4; ++rt)
#pragma unroll
        for (int tt = 0; tt < 2; ++tt)
          acc[rt][tt] = __builtin_amdgcn_mfma_f32_16x16x32_bf16(af[rt], bfr[tt], acc[rt][tt], 0, 0, 0);
    }
  }

  // acc -> wd[t][p] (pair-packed bf16, round-5 verified pattern)
#pragma unroll
  for (int rt = 0; rt < 4; ++rt) {
    int pbase = w * 32 + rt * 8 + qh * 2;
#pragma unroll
    for (int tt = 0; tt < 2; ++tt) {
      int t = tt * 16 + l15;
      f32x4 a4 = acc[rt][tt];
      *(uint2*)&wd[t * LDW + pbase] = make_uint2(pack2(a4[0], a4[1]), pack2(a4[2], a4[3]));
    }
  }

  // totals Tot_c = sum_t a^{31-t} w_t  (round-8 verified, register-only)
  {
    const float2* APT = (const float2*)(ws + APT_OFF);
    float2* Tot = (float2*)(ws + TOT_OFF);
#pragma unroll
    for (int rt = 0; rt < 4; ++rt) {
      int pbase = w * 32 + rt * 8 + qh * 2;
      float s0r = 0.f, s0i = 0.f, s1r = 0.f, s1i = 0.f;
#pragma unroll
      for (int tt = 0; tt < 2; ++tt) {
        int t = tt * 16 + l15;
        f32x4 a4 = acc[rt][tt];
        float2 awa = APT[(LCH - 1 - t) * 128 + pbase];
        float2 awb = APT[(LCH - 1 - t) * 128 + pbase + 1];
        s0r += a4[0] * awa.x - a4[1] * awa.y;
        s0i += a4[0] * awa.y + a4[1] * awa.x;
        s1r += a4[2] * awb.x - a4[3] * awb.y;
        s1i += a4[2] * awb.y + a4[3] * awb.x;
      }
#pragma unroll
      for (int m = 1; m < 16; m <<= 1) {
        s0r += __shfl_xor(s0r, m); s0i += __shfl_xor(s0i, m);
        s1r += __shfl_xor(s1r, m); s1i += __shfl_xor(s1i, m);
      }
      if (l15 == 0) {
        Tot[(c * BSZ + b) * 128 + pbase]     = make_float2(s0r, s0i);
        Tot[(c * BSZ + b) * 128 + pbase + 1] = make_float2(s1r, s1i);
      }
    }
  }
  __syncthreads();

  // wd -> W global, fully coalesced 16 KB per block (round-8 verified pattern)
  {
    unsigned int* Wg = (unsigned int*)(ws + W_OFF);
    const size_t wbase = (size_t)(c * BSZ + b) * (LCH * 128);
#pragma unroll
    for (int i = 0; i < 16; ++i) {
      int idx = tid + i * 256;
      int t = idx >> 7, p = idx & 127;
      Wg[wbase + t * 128 + p] = wd[t * LDW + p];
    }
  }
}

// ---------------------------------------------------------------------------
// K3: carry (2-half split + ILP-4) -> seeded scan (W contiguous) -> GEMM2
//     -> outT bf16. Grid (NCH, BSZ) = 1024 blocks, LDS 17.9 KB.
// ---------------------------------------------------------------------------
__global__ __launch_bounds__(256) void k3_main(
    const float* __restrict__ ws_c, float* __restrict__ ws) {
  __shared__ __align__(16) unsigned int wd[LCH * LDW];
  __shared__ float pshare[256];
  const int c = blockIdx.x, b = blockIdx.y;
  const int t0 = c * LCH;
  const int tid = threadIdx.x;
  const int L = tid & 63;
  const int w = __builtin_amdgcn_readfirstlane(tid >> 6);
  const int qh = L >> 4, l15 = L & 15;
  const int p = tid & 127, hf = tid >> 7;

  // carry = sum_{cp<c} (a^32)^{c-1-cp} * Tot_{cp}; split over halves, ILP-4
  float cr = 0.f, ci = 0.f;
  {
    const float2* ALp = (const float2*)(ws_c + ALP_OFF);
    const float2* Tot = (const float2*)(ws_c + TOT_OFF);
    const int beg = hf ? (c >> 1) : 0;
    const int end = hf ? c : (c >> 1);
    float a0r = 0.f, a0i = 0.f, a1r = 0.f, a1i = 0.f;
    float a2r = 0.f, a2i = 0.f, a3r = 0.f, a3i = 0.f;
    int cp = beg;
    for (; cp + 4 <= end; cp += 4) {
      float2 l0 = ALp[(c - 1 - cp) * 128 + p], v0 = Tot[((cp    ) * BSZ + b) * 128 + p];
      float2 l1 = ALp[(c - 2 - cp) * 128 + p], v1 = Tot[((cp + 1) * BSZ + b) * 128 + p];
      float2 l2 = ALp[(c - 3 - cp) * 128 + p], v2 = Tot[((cp + 2) * BSZ + b) * 128 + p];
      float2 l3 = ALp[(c - 4 - cp) * 128 + p], v3 = Tot[((cp + 3) * BSZ + b) * 128 + p];
      a0r = fmaf(l0.x, v0.x, fmaf(-l0.y, v0.y, a0r)); a0i = fmaf(l0.x, v0.y, fmaf(l0.y, v0.x, a0i));
      a1r = fmaf(l1.x, v1.x, fmaf(-l1.y, v1.y, a1r)); a1i = fmaf(l1.x, v1.y, fmaf(l1.y, v1.x, a1i));
      a2r = fmaf(l2.x, v2.x, fmaf(-l2.y, v2.y, a2r)); a2i = fmaf(l2.x, v2.y, fmaf(l2.y, v2.x, a2i));
      a3r = fmaf(l3.x, v3.x, fmaf(-l3.y, v3.y, a3r)); a3i = fmaf(l3.x, v3.y, fmaf(l3.y, v3.x, a3i));
    }
    for (; cp < end; ++cp) {
      float2 l0 = ALp[(c - 1 - cp) * 128 + p], v0 = Tot[(cp * BSZ + b) * 128 + p];
      a0r = fmaf(l0.x, v0.x, fmaf(-l0.y, v0.y, a0r)); a0i = fmaf(l0.x, v0.y, fmaf(l0.y, v0.x, a0i));
    }
    cr = (a0r + a1r) + (a2r + a3r);
    ci = (a0i + a1i) + (a2i + a3i);
  }
  if (hf) { pshare[p] = cr; pshare[p + 128] = ci; }
  __syncthreads();
  if (!hf) {
    cr += pshare[p]; ci += pshare[p + 128];
    // seeded scan: z_{-1} = carry (round-5 verified recurrence)
    const unsigned int* Wg = (const unsigned int*)(ws_c + W_OFF);
    const size_t wbase = (size_t)(c * BSZ + b) * (LCH * 128);
    float2 a = ((const float2*)(ws_c + APT_OFF))[128 + p];   // a^1
    float zr = cr, zi = ci;
#pragma unroll
    for (int t = 0; t < LCH; ++t) {
      unsigned int wv = Wg[wbase + t * 128 + p];
      float wr = bfbits2f(wv & 0xffffu), wi = bfbits2f(wv >> 16);
      float nr = fmaf(a.x, zr, fmaf(-a.y, zi, wr));
      float ni = fmaf(a.x, zi, fmaf(a.y, zr, wi));
      zr = nr; zi = ni;
      wd[t * LDW + p] = pack2(zr, zi);
    }
  }
  __syncthreads();

  // GEMM2: out_tile = C2 @ Z (round-4 verified)
  f32x4 acc[4][2];
#pragma unroll
  for (int rt = 0; rt < 4; ++rt)
#pragma unroll
    for (int tt = 0; tt < 2; ++tt) acc[rt][tt] = (f32x4){0.f, 0.f, 0.f, 0.f};
  {
    const unsigned short* Cbf = (const unsigned short*)(ws_c + CB_OFF);
    const unsigned short* zs  = (const unsigned short*)wd;
#pragma unroll
    for (int ks = 0; ks < 8; ++ks) {
      short8 af[4], bfr[2];
#pragma unroll
      for (int rt = 0; rt < 4; ++rt)
        af[rt] = *(const short8*)(Cbf + (size_t)(w * 64 + rt * 16 + l15) * 256 + ks * 32 + qh * 8);
#pragma unroll
      for (int tt = 0; tt < 2; ++tt)
        bfr[tt] = *(const short8*)(zs + (tt * 16 + l15) * LDK + ks * 32 + qh * 8);
#pragma unroll
      for (int rt = 0; rt < 4; ++rt)
#pragma unroll
        for (int tt = 0; tt < 2; ++tt)
          acc[rt][tt] = __builtin_amdgcn_mfma_f32_16x16x32_bf16(af[rt], bfr[tt], acc[rt][tt], 0, 0, 0);
    }
  }
  __syncthreads();   // all z reads done before overwrite

  // acc (D-layout) -> LDS bf16 [t][Do] -> contiguous outT write (verified)
#pragma unroll
  for (int rt = 0; rt < 4; ++rt) {
    int uidx = w * 32 + rt * 8 + qh * 2;
#pragma unroll
    for (int tt = 0; tt < 2; ++tt) {
      int t = tt * 16 + l15;
      f32x4 a4 = acc[rt][tt];
      wd[t * LDW + uidx]     = pack2(a4[0], a4[1]);
      wd[t * LDW + uidx + 1] = pack2(a4[2], a4[3]);
    }
  }
  __syncthreads();
  {
    unsigned int* OTg = (unsigned int*)(ws + OT_OFF);
#pragma unroll
    for (int i = 0; i < 16; ++i) {
      int idx = tid + i * 256;            // 32 rows x 128 uints
      int t = idx >> 7, col = idx & 127;
      OTg[((size_t)(b * TLEN + t0 + t)) * 128 + col] = wd[t * LDW + col];
    }
  }
}

// ---------------------------------------------------------------------------
// K4: out[b][Do][t] = bf2f(outT[b][t][Do]) + D[Do]*u[b][Do][t]. (round-8
// verbatim — verified) Grid (16,4,8), LDS 33.8 KB.
// ---------------------------------------------------------------------------
__global__ __launch_bounds__(256) void k4_out(
    const float* __restrict__ u, const float* __restrict__ Dv,
    const float* __restrict__ ws, float* __restrict__ out) {
  __shared__ unsigned short tile[256 * 66];   // [t][Do_local], pad 2
  const int tc = blockIdx.x, dc = blockIdx.y, b = blockIdx.z;
  const int tid = threadIdx.x;
  const unsigned int* OTg = (const unsigned int*)(ws + OT_OFF);

#pragma unroll
  for (int i = 0; i < 32; ++i) {
    int idx = tid + i * 256;               // 256 t x 32 uints
    int t = idx >> 5, col = idx & 31;
    unsigned int v = OTg[((size_t)(b * TLEN + tc * 256 + t)) * 128 + dc * 32 + col];
    *(unsigned int*)(tile + t * 66 + 2 * col) = v;
  }
  __syncthreads();

  const int w = tid >> 6, lane = tid & 63;
#pragma unroll
  for (int i = 0; i < 16; ++i) {
    int dl = i * 4 + w;
    int Do = dc * 64 + dl;
    float dv = Dv[Do];
    size_t base = (size_t)(b * 256 + Do) * TLEN + tc * 256 + lane * 4;
    float4 uu = *(const float4*)(u + base);
    float4 o;
    o.x = bfbits2f(tile[(lane * 4 + 0) * 66 + dl]) + dv * uu.x;
    o.y = bfbits2f(tile[(lane * 4 + 1) * 66 + dl]) + dv * uu.y;
    o.z = bfbits2f(tile[(lane * 4 + 2) * 66 + dl]) + dv * uu.z;
    o.w = bfbits2f(tile[(lane * 4 + 3) * 66 + dl]) + dv * uu.w;
    *(float4*)(out + base) = o;
  }
}

extern "C" void kernel_launch(void* const* d_in, const int* in_sizes, int n_in,
                              void* d_out, int out_size, void* d_ws, size_t ws_size,
                              hipStream_t stream) {
  const float* u          = (const float*)d_in[0];
  const float* thetas_log = (const float*)d_in[1];
  const float* P_param    = (const float*)d_in[2];
  const float* B_param    = (const float*)d_in[3];
  const float* C          = (const float*)d_in[4];
  const float* Dvec       = (const float*)d_in[5];
  const float* gamma_log  = (const float*)d_in[6];
  float* out = (float*)d_out;
  float* ws  = (float*)d_ws;

  hipLaunchKernelGGL(k0t_setup, dim3(32 + 512), dim3(256), 0, stream,
                     thetas_log, P_param, B_param, C, gamma_log, u, ws);
  hipLaunchKernelGGL(k1_tot, dim3(NCH, BSZ), dim3(256), 0, stream, ws);
  hipLaunchKernelGGL(k3_main, dim3(NCH, BSZ), dim3(256), 0, stream, ws, ws);
  hipLaunchKernelGGL(k4_out, dim3(16, 4, BSZ), dim3(256), 0, stream,
                     u, Dvec, ws, out);
}